// Round 2
// baseline (54626.978 us; speedup 1.0000x reference)
//
#include <hip/hip_runtime.h>
#include <hip/hip_bf16.h>
#include <math.h>

// WaveNet autoregressive generation, MI355X, fp32 (argmax feedback forbids
// low-precision; no fp32 MFMA on CDNA4 -> vector ALU kernel).
//
// One WG of 1024 threads (16 waves) per batch element. The run is
// latency-bound on the per-element serial chain, so the design minimizes
// critical-path latency: 4-way split dots (depth-16 chains + shfl_xor
// reduce), dilation-queue pops prefetched one step ahead (hidden under the
// output head), queue pushes batched off the per-layer barriers via an LDS
// x-history tape, 3 barriers/layer.

#define NL 30
#define NC 64
#define NS 256
#define NV 256
#define NB 128
#define QTOT 3069   // sum of dilations: 3 * (2^10 - 1)
#define NT 1024

// Per-batch dilation queues in static device memory (~100.6 MB).
// Slot for layer l at step t is written at t and read at t+d; reads gated by
// (t >= d) so stale cross-launch contents are never observed.
__device__ float g_queues[(size_t)NB * QTOT * NC];

__device__ __forceinline__ void layer_params(int l, int& d, int& qo) {
  const int a = (l >= 20) ? 2 : ((l >= 10) ? 1 : 0);
  const int bb = l - a * 10;
  d = 1 << bb;
  qo = a * 1023 + (d - 1);
}

__global__ __launch_bounds__(NT, 1)
void wavenet_gen_kernel(const int* __restrict__ seed,
                        const float* __restrict__ emb,     // (V, C)
                        const float* __restrict__ kern,    // (L, 2, C, 2C)
                        const float* __restrict__ cbias,   // (L, 2C)
                        const float* __restrict__ resw,    // (L, C, C)
                        const float* __restrict__ resb,    // (L, C)
                        const float* __restrict__ skipw,   // (L, C, S)
                        const float* __restrict__ skipb,   // (L, S)
                        const float* __restrict__ w0,      // (S, V)
                        const float* __restrict__ b0,      // (V)
                        const float* __restrict__ w1,      // (V, V)
                        const float* __restrict__ b1,      // (V)
                        const int* __restrict__ pT,
                        float* __restrict__ out)
{
  const int b   = blockIdx.x;
  const int t_  = threadIdx.x;
  const int T   = pT[0];

  const int j    = t_ >> 2;    // dot index (0..255)
  const int p    = t_ & 3;     // 4-way depth split
  const int half = j >> 7;     // conv: K0 (x_last) vs K1 (x)
  const int col  = j & 127;    // conv output column
  const int lane = t_ & 63;
  const int wv   = t_ >> 6;

  __shared__ float sxlAll[NL][NC];   // prefetched x_last for every layer
  __shared__ float xHist[NL][NC];    // layer-input tape (push source)
  __shared__ float hp[2][2 * NC];    // conv half-partials
  __shared__ float sg[NC];           // gated activation
  __shared__ float sskip[NS];
  __shared__ float sh0[NV];
  __shared__ float rv[16];
  __shared__ int   ri[16];
  __shared__ int   snext;

  // ---- init: step-0 pops are all zeros (t < d for every layer) ----
  ((float*)sxlAll)[t_] = 0.f;
  if (t_ < (NL * NC - NT)) ((float*)sxlAll)[t_ + NT] = 0.f;
  if (t_ < NC) xHist[0][t_] = emb[(size_t)seed[b] * NC + t_];
  __syncthreads();

  float* __restrict__ q = g_queues + (size_t)b * QTOT * NC;
  const size_t logits_base = (size_t)NB * (size_t)T;

  for (int t = 0; t < T; ++t) {
    float skipacc = 0.f;

    for (int i = 0; i < NL; ++i) {
      // ---- conv: 256 dots (2 halves x 128 cols), depth 64, 4-way split ----
      {
        const float* __restrict__ W =
            kern + ((size_t)(i * 2 + half)) * NC * (2 * NC) + col;
        const float* __restrict__ xv = half ? xHist[i] : sxlAll[i];
        float acc = 0.f;
#pragma unroll
        for (int cc = 0; cc < 16; ++cc) {
          const int c = p * 16 + cc;
          acc = fmaf(xv[c], W[(size_t)c * (2 * NC)], acc);
        }
        acc += __shfl_xor(acc, 1);
        acc += __shfl_xor(acc, 2);
        if (p == 0) hp[half][col] = acc;
      }
      __syncthreads();

      // ---- gated: g = tanh(h[:64]) * sigmoid(h[64:]) (wave 0 only) ----
      if (t_ < NC) {
        const float ha = hp[0][t_] + hp[1][t_] + cbias[i * 2 * NC + t_];
        const float hb = hp[0][NC + t_] + hp[1][NC + t_] + cbias[i * 2 * NC + NC + t_];
        sg[t_] = tanhf(ha) * (1.f / (1.f + expf(-hb)));
      }
      __syncthreads();

      // ---- skip (all 1024) + residual (waves 0..3), depth 64, 4-way ----
      {
        const float* __restrict__ SW = skipw + (size_t)i * NC * NS + j;
        float acc = 0.f;
#pragma unroll
        for (int cc = 0; cc < 16; ++cc) {
          const int c = p * 16 + cc;
          acc = fmaf(sg[c], SW[(size_t)c * NS], acc);
        }
        acc += __shfl_xor(acc, 1);
        acc += __shfl_xor(acc, 2);
        skipacc += acc + skipb[i * NS + j];  // identical in all 4 p-lanes
      }
      if (i < NL - 1 && t_ < 256) {  // layer 29's x output is dead -> skip res
        const float* __restrict__ RW = resw + (size_t)i * NC * NC + j;
        float acc = 0.f;
#pragma unroll
        for (int cc = 0; cc < 16; ++cc) {
          const int c = p * 16 + cc;
          acc = fmaf(sg[c], RW[(size_t)c * NC], acc);
        }
        acc += __shfl_xor(acc, 1);
        acc += __shfl_xor(acc, 2);
        if (p == 0) xHist[i + 1][j] = xHist[i][j] + acc + resb[i * NC + j];
      }
      if (i == NL - 1 && p == 0) sskip[j] = fmaxf(skipacc, 0.f);
      __syncthreads();
    }

    // ---- head; queue prefetch (t+1) + pushes (t) overlap the matmuls ----
    const int tp = t + 1;
    float rA = 0.f, rB = 0.f;
    {
      // loads first (avoid store->load alias waits), then pushes
      const int l0 = t_ >> 6;
      int d0, qo0; layer_params(l0, d0, qo0);
      if (d0 > 1 && tp >= d0)
        rA = q[(size_t)(qo0 + (tp & (d0 - 1))) * NC + lane];
      int l1 = l0 + 16, d1_ = 0, qo1 = 0;
      const bool has1 = (t_ < (NL * NC - NT));
      if (has1) {
        layer_params(l1, d1_, qo1);
        if (d1_ > 1 && tp >= d1_)
          rB = q[(size_t)(qo1 + (tp & (d1_ - 1))) * NC + lane];
      }
      const float xv0 = xHist[l0][lane];
      if (d0 == 1) rA = xv0;                     // d=1: LDS bypass, no global
      else q[(size_t)(qo0 + (t & (d0 - 1))) * NC + lane] = xv0;
      if (has1) {
        const float xv1 = xHist[l1][lane];
        if (d1_ == 1) rB = xv1;
        else q[(size_t)(qo1 + (t & (d1_ - 1))) * NC + lane] = xv1;
      }
    }

    // h0 = relu(skip @ w0 + b0): 256 dots depth 256, 4-way interleaved split
    {
      const float* __restrict__ W = w0 + j;
      float a0 = 0.f, a1 = 0.f;
#pragma unroll
      for (int cc = 0; cc < 64; cc += 2) {
        const int c0 = 4 * cc + p;
        const int c1 = 4 * (cc + 1) + p;
        a0 = fmaf(sskip[c0], W[(size_t)c0 * NV], a0);
        a1 = fmaf(sskip[c1], W[(size_t)c1 * NV], a1);
      }
      float acc = a0 + a1;
      acc += __shfl_xor(acc, 1);
      acc += __shfl_xor(acc, 2);
      if (p == 0) sh0[j] = fmaxf(acc + b0[j], 0.f);
    }
    __syncthreads();

    // logits = h0 @ w1 + b1
    float lg;
    {
      const float* __restrict__ W = w1 + j;
      float a0 = 0.f, a1 = 0.f;
#pragma unroll
      for (int cc = 0; cc < 64; cc += 2) {
        const int c0 = 4 * cc + p;
        const int c1 = 4 * (cc + 1) + p;
        a0 = fmaf(sh0[c0], W[(size_t)c0 * NV], a0);
        a1 = fmaf(sh0[c1], W[(size_t)c1 * NV], a1);
      }
      float acc = a0 + a1;
      acc += __shfl_xor(acc, 1);
      acc += __shfl_xor(acc, 2);
      lg = acc + b1[j];
      if (p == 0) out[logits_base + ((size_t)b * T + t) * NV + j] = lg;
    }

    // ---- argmax (first-max semantics; p-duplicates are identical) ----
    float v = lg; int ix = j;
#pragma unroll
    for (int o = 32; o > 0; o >>= 1) {
      const float ov = __shfl_down(v, o);
      const int   oi = __shfl_down(ix, o);
      if (ov > v || (ov == v && oi < ix)) { v = ov; ix = oi; }
    }
    if (lane == 0) { rv[wv] = v; ri[wv] = ix; }
    __syncthreads();
    if (t_ == 0) {
      float bv = rv[0]; int bi = ri[0];
#pragma unroll
      for (int w = 1; w < 16; ++w)
        if (rv[w] > bv || (rv[w] == bv && ri[w] < bi)) { bv = rv[w]; bi = ri[w]; }
      snext = bi;
      out[(size_t)b * T + t] = (float)bi;
    }
    __syncthreads();

    // ---- commit prefetched pops; embedding feedback ----
    ((float*)sxlAll)[t_] = rA;
    if (t_ < (NL * NC - NT)) ((float*)sxlAll)[t_ + NT] = rB;
    if (t_ < NC) xHist[0][t_] = emb[(size_t)snext * NC + t_];
    __syncthreads();
  }
}

extern "C" void kernel_launch(void* const* d_in, const int* in_sizes, int n_in,
                              void* d_out, int out_size, void* d_ws, size_t ws_size,
                              hipStream_t stream) {
  (void)in_sizes; (void)n_in; (void)out_size; (void)d_ws; (void)ws_size;
  wavenet_gen_kernel<<<NB, NT, 0, stream>>>(
      (const int*)d_in[0],   (const float*)d_in[1], (const float*)d_in[2],
      (const float*)d_in[3], (const float*)d_in[4], (const float*)d_in[5],
      (const float*)d_in[6], (const float*)d_in[7], (const float*)d_in[8],
      (const float*)d_in[9], (const float*)d_in[10], (const float*)d_in[11],
      (const int*)d_in[12],  (float*)d_out);
}

// Round 7
// 53558.966 us; speedup vs baseline: 1.0199x; 1.0199x over previous
//
#include <hip/hip_runtime.h>
#include <hip/hip_bf16.h>
#include <math.h>

// WaveNet autoregressive generation, MI355X, fp32 (argmax feedback forbids
// low-precision; no fp32 MFMA on CDNA4 -> vector ALU kernel).
//
// One WG of 1024 threads (16 waves, 4/SIMD) per batch element. Latency-bound
// on the per-element serial chain -> maximize latency hiding while keeping
// every weight load wave-coalesced (256B):
//   RULE: depth-slice index lives in the WAVE id (wave-uniform), column index
//   lives in the LANE id. Round 2 violated this (p in low bits) -> 2.4x
//   overfetch + 4x stalls.
// Cross-slice reduces: LDS partials at existing barriers; skip partials kept
// in private registers and reduced ONCE per step before the head.
// Dilation-queue pops are prefetched one step ahead (hidden under the output
// head); pushes batched there too via the xHist LDS tape. 3 barriers/layer.

#define NL 30
#define NC 64
#define NS 256
#define NV 256
#define NB 128
#define QTOT 3069   // sum of dilations: 3 * (2^10 - 1)
#define NT 1024

// Per-batch dilation queues (~100.6 MB) in static device memory. Slot for
// layer l is written at step t and read at step t+d; reads gated by (t >= d)
// so stale cross-launch contents are never observed (re-poison safe).
__device__ float g_queues[(size_t)NB * QTOT * NC];

__device__ __forceinline__ void layer_params(int l, int& d, int& qo) {
  const int a = (l >= 20) ? 2 : ((l >= 10) ? 1 : 0);
  const int bb = l - a * 10;
  d = 1 << bb;
  qo = a * 1023 + (d - 1);
}

__global__ __launch_bounds__(NT, 1)
void wavenet_gen_kernel(const int* __restrict__ seed,
                        const float* __restrict__ emb,     // (V, C)
                        const float* __restrict__ kern,    // (L, 2, C, 2C)
                        const float* __restrict__ cbias,   // (L, 2C)
                        const float* __restrict__ resw,    // (L, C, C)
                        const float* __restrict__ resb,    // (L, C)
                        const float* __restrict__ skipw,   // (L, C, S)
                        const float* __restrict__ skipb,   // (L, S)
                        const float* __restrict__ w0,      // (S, V)
                        const float* __restrict__ b0,      // (V)
                        const float* __restrict__ w1,      // (V, V)
                        const float* __restrict__ b1,      // (V)
                        const int* __restrict__ pT,
                        float* __restrict__ out)
{
  const int b    = blockIdx.x;
  const int t_   = threadIdx.x;
  const int T    = pT[0];
  const int lane = t_ & 63;
  const int w    = t_ >> 6;          // wave 0..15

  // conv mapping: wave -> (half, col-half, depth-slice); lane -> column
  const int cv_half = w & 1;
  const int cv_col  = ((w >> 1) & 1) * 64 + lane;   // 0..127
  const int cv_p    = w >> 2;                        // 0..3
  // skip/head mapping: wave -> (depth-slice, col-chunk); lane -> column
  const int sk_p    = w >> 2;                        // 0..3
  const int sk_j    = (w & 3) * 64 + lane;           // 0..255

  __shared__ float sxlAll[NL][NC];   // prefetched x_last per layer
  __shared__ float xHist[NL][NC];    // layer-input tape (queue push source)
  __shared__ float hpc[4][2][2 * NC];// conv partials [slice][half][col]
  __shared__ float sg[NC];           // gated activation
  __shared__ float sp[4][NS];        // skip partials (once per step)
  __shared__ float sskip[NS];
  __shared__ float hh[4][NV];        // head partials (reused by both matmuls)
  __shared__ float sh0[NV];
  __shared__ float rv[4];
  __shared__ int   ri[4];
  __shared__ int   snext;

  // step-0 pops are all zeros (t=0 < d for every layer)
  ((float*)sxlAll)[t_] = 0.f;
  if (t_ < (NL * NC - NT)) ((float*)sxlAll)[t_ + NT] = 0.f;
  if (t_ < NC) xHist[0][t_] = emb[(size_t)seed[b] * NC + t_];
  __syncthreads();

  float* __restrict__ q = g_queues + (size_t)b * QTOT * NC;
  const size_t logits_base = (size_t)NB * (size_t)T;

  for (int t = 0; t < T; ++t) {
    float skipacc = 0.f;   // private partial: depth-slice sk_p of column sk_j

    for (int i = 0; i < NL; ++i) {
      // ---- conv partials: lane=col (coalesced 256B), wave-uniform slice ----
      {
        const float* __restrict__ W =
            kern + ((size_t)(i * 2 + cv_half)) * (NC * 2 * NC) + cv_col;
        const float* __restrict__ xv = cv_half ? xHist[i] : sxlAll[i];
        float acc = 0.f;
#pragma unroll
        for (int cc = 0; cc < 16; ++cc) {
          const int c = cv_p * 16 + cc;                 // wave-uniform row
          acc = fmaf(xv[c], W[(size_t)c * (2 * NC)], acc);
        }
        hpc[cv_p][cv_half][cv_col] = acc;
      }
      __syncthreads();

      // ---- gate: sum 8 partials per column, tanh*sigmoid (1 wave) ----
      if (t_ < NC) {
        float ha = cbias[i * 2 * NC + t_];
        float hb = cbias[i * 2 * NC + NC + t_];
#pragma unroll
        for (int p = 0; p < 4; ++p) {
          ha += hpc[p][0][t_]      + hpc[p][1][t_];
          hb += hpc[p][0][NC + t_] + hpc[p][1][NC + t_];
        }
        sg[t_] = tanhf(ha) * (1.f / (1.f + expf(-hb)));
      }
      __syncthreads();

      // ---- skip partial (all 16 waves, coalesced, private accumulate) ----
      {
        const float* __restrict__ SW = skipw + (size_t)i * NC * NS + sk_j;
        float acc = 0.f;
#pragma unroll
        for (int cc = 0; cc < 16; ++cc) {
          const int c = sk_p * 16 + cc;
          acc = fmaf(sg[c], SW[(size_t)c * NS], acc);
        }
        skipacc += acc;
        if (sk_p == 0) skipacc += skipb[i * NS + sk_j];
      }
      // ---- residual (waves 0..3): 16 cols x 4 in-wave depth slices ----
      if (w < 4 && i < NL - 1) {   // layer 29's x output is dead
        const int rcol = w * 16 + (lane & 15);
        const int rp   = lane >> 4;
        const float* __restrict__ RW = resw + (size_t)i * NC * NC + rcol;
        float racc = 0.f;
#pragma unroll
        for (int cc = 0; cc < 16; ++cc) {
          const int c = rp * 16 + cc;
          racc = fmaf(sg[c], RW[(size_t)c * NC], racc);
        }
        racc += __shfl_xor(racc, 16);
        racc += __shfl_xor(racc, 32);
        if (lane < 16)
          xHist[i + 1][rcol] = xHist[i][rcol] + racc + resb[i * NC + rcol];
      }
      __syncthreads();
    }

    // ================= head (queue traffic overlapped) =================
    // H0: park skip partials; prefetch step-(t+1) pops; push step-t values
    sp[sk_p][sk_j] = skipacc;
    const int tp = t + 1;
    float rA = 0.f, rB = 0.f;
    {
      const int l0 = w;                    // wave <-> layer
      int d0, qo0; layer_params(l0, d0, qo0);
      if (d0 > 1 && tp >= d0)
        rA = q[(size_t)(qo0 + (tp & (d0 - 1))) * NC + lane];
      int l1 = l0 + 16, d1_ = 0, qo1 = 0;
      const bool has1 = (t_ < (NL * NC - NT));
      if (has1) {
        layer_params(l1, d1_, qo1);
        if (d1_ > 1 && tp >= d1_)
          rB = q[(size_t)(qo1 + (tp & (d1_ - 1))) * NC + lane];
      }
      const float xv0 = xHist[l0][lane];
      if (d0 == 1) rA = xv0;               // d=1: LDS bypass
      else q[(size_t)(qo0 + (t & (d0 - 1))) * NC + lane] = xv0;
      if (has1) {
        const float xv1 = xHist[l1][lane];
        if (d1_ == 1) rB = xv1;
        else q[(size_t)(qo1 + (t & (d1_ - 1))) * NC + lane] = xv1;
      }
    }
    __syncthreads();

    // H1: finalize skip
    if (t_ < NS)
      sskip[t_] = fmaxf(sp[0][t_] + sp[1][t_] + sp[2][t_] + sp[3][t_], 0.f);
    __syncthreads();

    // H2: h0 partials (depth 256, 4 wave-uniform slices of 64)
    {
      const float* __restrict__ W = w0 + sk_j;
      float acc = 0.f;
#pragma unroll
      for (int cc = 0; cc < 64; ++cc) {
        const int c = sk_p * 64 + cc;
        acc = fmaf(sskip[c], W[(size_t)c * NV], acc);
      }
      hh[sk_p][sk_j] = acc;
    }
    __syncthreads();

    // H3: finalize h0
    if (t_ < NV)
      sh0[t_] = fmaxf(hh[0][t_] + hh[1][t_] + hh[2][t_] + hh[3][t_] + b0[t_], 0.f);
    __syncthreads();

    // H4: logits partials (reuse hh)
    {
      const float* __restrict__ W = w1 + sk_j;
      float acc = 0.f;
#pragma unroll
      for (int cc = 0; cc < 64; ++cc) {
        const int c = sk_p * 64 + cc;
        acc = fmaf(sh0[c], W[(size_t)c * NV], acc);
      }
      hh[sk_p][sk_j] = acc;
    }
    __syncthreads();

    // H5: finalize logits, store, argmax (first-max semantics)
    if (t_ < NV) {
      const float lg = hh[0][t_] + hh[1][t_] + hh[2][t_] + hh[3][t_] + b1[t_];
      out[logits_base + ((size_t)b * T + t) * NV + t_] = lg;
      float v = lg; int ix = t_;
#pragma unroll
      for (int o = 32; o > 0; o >>= 1) {
        const float ov = __shfl_down(v, o);
        const int   oi = __shfl_down(ix, o);
        if (ov > v || (ov == v && oi < ix)) { v = ov; ix = oi; }
      }
      if (lane == 0) { rv[w] = v; ri[w] = ix; }
    }
    __syncthreads();
    if (t_ == 0) {
      float bv = rv[0]; int bi = ri[0];
#pragma unroll
      for (int k = 1; k < 4; ++k)
        if (rv[k] > bv || (rv[k] == bv && ri[k] < bi)) { bv = rv[k]; bi = ri[k]; }
      snext = bi;
      out[(size_t)b * T + t] = (float)bi;
    }
    __syncthreads();

    // H6: commit prefetched pops; embedding feedback
    ((float*)sxlAll)[t_] = rA;
    if (t_ < (NL * NC - NT)) ((float*)sxlAll)[t_ + NT] = rB;
    if (t_ < NC) xHist[0][t_] = emb[(size_t)snext * NC + t_];
    __syncthreads();
  }
}

extern "C" void kernel_launch(void* const* d_in, const int* in_sizes, int n_in,
                              void* d_out, int out_size, void* d_ws, size_t ws_size,
                              hipStream_t stream) {
  (void)in_sizes; (void)n_in; (void)out_size; (void)d_ws; (void)ws_size;
  wavenet_gen_kernel<<<NB, NT, 0, stream>>>(
      (const int*)d_in[0],   (const float*)d_in[1], (const float*)d_in[2],
      (const float*)d_in[3], (const float*)d_in[4], (const float*)d_in[5],
      (const float*)d_in[6], (const float*)d_in[7], (const float*)d_in[8],
      (const float*)d_in[9], (const float*)d_in[10], (const float*)d_in[11],
      (const int*)d_in[12],  (float*)d_out);
}